// Round 1
// baseline (758.265 us; speedup 1.0000x reference)
//
#include <hip/hip_runtime.h>

#define NTOK 2048
#define NB 4
#define NH 8
#define DH 128

typedef __bf16 bf16x8 __attribute__((ext_vector_type(8)));
typedef unsigned short u16x8 __attribute__((ext_vector_type(8)));
typedef float f32x4 __attribute__((ext_vector_type(4)));

__device__ __forceinline__ f32x4 mfma16(bf16x8 a, bf16x8 b, f32x4 c) {
  return __builtin_amdgcn_mfma_f32_16x16x32_bf16(a, b, c, 0, 0, 0);
}
__device__ __forceinline__ bf16x8 ldb(const unsigned short* p) {
  return __builtin_bit_cast(bf16x8, *(const u16x8*)p);
}
__device__ __forceinline__ unsigned short f2bf(float f) {
  unsigned int u = __builtin_bit_cast(unsigned int, f);
  u += 0x7fffu + ((u >> 16) & 1u);
  return (unsigned short)(u >> 16);
}
// flag: 0 = int32, 1 = uint8, 2 = float32
__device__ __forceinline__ bool mask_at(const void* p, int flag, int idx) {
  if (flag == 1) return ((const unsigned char*)p)[idx] != 0;
  if (flag == 0) return ((const int*)p)[idx] != 0;
  return ((const float*)p)[idx] != 0.0f;
}

// ---- dtype detection: scan first 16384 dwords of attn_mask ----
__global__ void k_detect(const unsigned int* dw, int* flag) {
  __shared__ int su8, sf32;
  if (threadIdx.x == 0) { su8 = 0; sf32 = 0; }
  __syncthreads();
  int lu8 = 0, lf32 = 0;
  for (int i = threadIdx.x; i < 16384; i += blockDim.x) {
    unsigned int v = dw[i];
    if (v == 0x3f800000u) lf32 = 1;          // float 1.0
    else if (v != 0u && v != 1u) lu8 = 1;    // bytes set beyond byte0 -> u8 layout
  }
  if (lu8) atomicOr(&su8, 1);
  if (lf32) atomicOr(&sf32, 1);
  __syncthreads();
  if (threadIdx.x == 0) *flag = sf32 ? 2 : (su8 ? 1 : 0);
}

__global__ void k_cvt_x(const float* __restrict__ x, unsigned short* __restrict__ xb, int n) {
  int i = blockIdx.x * blockDim.x + threadIdx.x;
  if (i < n) xb[i] = f2bf(x[i]);
}

// w: [R][C] f32 -> wt: [C][R] bf16
__global__ void k_transpose_w(const float* __restrict__ w, unsigned short* __restrict__ wt, int R, int C) {
  int i = blockIdx.x * blockDim.x + threadIdx.x;
  if (i < R * C) {
    int c = i / R, r = i - c * R;
    wt[i] = f2bf(w[(size_t)r * C + c]);
  }
}

// pack attn_mask into bit array: bit j of word w = element w*32+j
__global__ void k_pack_mask(const void* __restrict__ am, const int* __restrict__ flagp,
                            unsigned int* __restrict__ bits, int n) {
  int flag = *flagp;
  int i = blockIdx.x * blockDim.x + threadIdx.x;
  bool v = (i < n) ? mask_at(am, flag, i) : false;
  unsigned long long bm = __ballot(v);
  int lane = threadIdx.x & 63;
  if (lane == 0) bits[i >> 5] = (unsigned int)bm;
  else if (lane == 32) bits[i >> 5] = (unsigned int)(bm >> 32);
}

// ---- QKV projection: [8192,128] @ [128,1024] per weight; K=128 in one pass ----
__global__ __launch_bounds__(256) void k_gemm_qkv(
    const unsigned short* __restrict__ xb, const unsigned short* __restrict__ wqt,
    const unsigned short* __restrict__ wkt, const unsigned short* __restrict__ wvt,
    unsigned short* __restrict__ qb, unsigned short* __restrict__ kbuf,
    unsigned short* __restrict__ vtb) {
  int which = blockIdx.z;
  const unsigned short* wt = which == 0 ? wqt : (which == 1 ? wkt : wvt);
  int lane = threadIdx.x & 63, w = threadIdx.x >> 6;
  int lo = lane & 15, g = lane >> 4;
  int rbase = blockIdx.x * 64 + w * 16;
  int colb = blockIdx.y * 128;
  bf16x8 af[4];
  const unsigned short* xrow = xb + (size_t)(rbase + lo) * 128 + g * 8;
#pragma unroll
  for (int s = 0; s < 4; s++) af[s] = ldb(xrow + 32 * s);
  f32x4 acc[8] = {};
#pragma unroll
  for (int c = 0; c < 8; c++) {
    const unsigned short* wrow = wt + (size_t)(colb + c * 16 + lo) * 128 + g * 8;
#pragma unroll
    for (int s = 0; s < 4; s++) acc[c] = mfma16(af[s], ldb(wrow + 32 * s), acc[c]);
  }
#pragma unroll
  for (int c = 0; c < 8; c++) {
#pragma unroll
    for (int r = 0; r < 4; r++) {
      int row = rbase + 4 * g + r;            // D-layout: row=(lane>>4)*4+reg
      int col = colb + c * 16 + lo;           //           col=lane&15
      int b = row >> 11, n = row & (NTOK - 1);
      int h = col >> 7, d = col & 127;
      unsigned short val = f2bf(acc[c][r]);
      size_t bh = (size_t)(b * NH + h);
      if (which == 2)      vtb[(bh * DH + d) * NTOK + n] = val;   // V transposed [bh][d][n]
      else if (which == 0) qb[(bh * NTOK + n) * DH + d] = val;
      else                 kbuf[(bh * NTOK + n) * DH + d] = val;
    }
  }
}

// ---- flash attention, swapped QK^T (S^T = K·Q^T) ----
__global__ __launch_bounds__(256) void k_attn(
    const unsigned short* __restrict__ qb, const unsigned short* __restrict__ kbuf,
    const unsigned short* __restrict__ vtb, const unsigned int* __restrict__ mbits,
    unsigned short* __restrict__ aout) {
  int bid = blockIdx.x;              // 1024 = 32 bh * 32 qchunks
  int bh = bid >> 5, qc = bid & 31;
  int b = bh >> 3, h = bh & 7;
  int lane = threadIdx.x & 63, w = threadIdx.x >> 6;
  int lo = lane & 15, g = lane >> 4;
  int q0 = qc * 64 + w * 16;
  const unsigned short* Q = qb + (size_t)bh * NTOK * DH;
  const unsigned short* K = kbuf + (size_t)bh * NTOK * DH;
  const unsigned short* VT = vtb + (size_t)bh * NTOK * DH;
  bf16x8 qf[4];
  {
    const unsigned short* qrow = Q + (size_t)(q0 + lo) * DH + g * 8;
#pragma unroll
    for (int s = 0; s < 4; s++) qf[s] = ldb(qrow + 32 * s);
  }
  f32x4 o[8] = {};
  float m = -3.0e38f, l = 0.0f;
  const float scale = 0.08838834764831845f;   // 1/sqrt(128)
  int qrow_g = q0 + lo;
  const unsigned int* mrow = mbits + (size_t)b * (NTOK * NTOK / 32) + (size_t)qrow_g * (NTOK / 32);
  int kl4 = 4 * g;
  for (int kb0 = 0; kb0 < NTOK; kb0 += 32) {
    f32x4 s0 = {}, s1 = {};
    const unsigned short* krow = K + (size_t)(kb0 + lo) * DH + g * 8;
#pragma unroll
    for (int s = 0; s < 4; s++) {
      s0 = mfma16(ldb(krow + 32 * s), qf[s], s0);             // keys kb0..kb0+15
      s1 = mfma16(ldb(krow + 16 * DH + 32 * s), qf[s], s1);   // keys kb0+16..31
    }
    unsigned int mw = mrow[kb0 >> 5];
    // lane holds keys kb0+4g+r (s0) and +16 (s1), column q = q0+lo
    float sv0[4], sv1[4];
    float mx = -3.0e38f;
#pragma unroll
    for (int r = 0; r < 4; r++) {
      bool v0 = (mw >> (kl4 + r)) & 1;
      bool v1 = (mw >> (16 + kl4 + r)) & 1;
      sv0[r] = v0 ? s0[r] * scale : -3.0e38f;
      sv1[r] = v1 ? s1[r] * scale : -3.0e38f;
      mx = fmaxf(mx, fmaxf(sv0[r], sv1[r]));
    }
    mx = fmaxf(mx, __shfl_xor(mx, 16, 64));
    mx = fmaxf(mx, __shfl_xor(mx, 32, 64));
    float mnew = fmaxf(m, mx);
    float corr = __expf(m - mnew);
    float p0[4], p1[4];
    float ps = 0.f;
#pragma unroll
    for (int r = 0; r < 4; r++) {
      bool v0 = (mw >> (kl4 + r)) & 1;
      bool v1 = (mw >> (16 + kl4 + r)) & 1;
      p0[r] = v0 ? __expf(sv0[r] - mnew) : 0.f;   // explicit gate: handles all-masked rows
      p1[r] = v1 ? __expf(sv1[r] - mnew) : 0.f;
      ps += p0[r] + p1[r];
    }
    ps += __shfl_xor(ps, 16, 64);
    ps += __shfl_xor(ps, 32, 64);
    l = l * corr + ps;
    m = mnew;
    // rescale O rows (row index q_o = 4g+r): fetch corr of q=q_o from lane (g*16 + 4g + r)
    float co[4];
#pragma unroll
    for (int r = 0; r < 4; r++) co[r] = __shfl(corr, (lane & 48) + kl4 + r, 64);
#pragma unroll
    for (int t = 0; t < 8; t++) {
      o[t][0] *= co[0]; o[t][1] *= co[1]; o[t][2] *= co[2]; o[t][3] *= co[3];
    }
    // redistribute P^T (D-layout) -> PV A-fragment: q stays in lane&15
    int srcA = ((g & 1) * 2) * 16 + lo;
    int srcB = srcA + 16;
    bool hi = g >= 2;
    u16x8 pu;
#pragma unroll
    for (int r = 0; r < 4; r++) {
      float a0 = __shfl(p0[r], srcA, 64);
      float a1 = __shfl(p1[r], srcA, 64);
      float b0 = __shfl(p0[r], srcB, 64);
      float b1 = __shfl(p1[r], srcB, 64);
      pu[r] = f2bf(hi ? a1 : a0);
      pu[4 + r] = f2bf(hi ? b1 : b0);
    }
    bf16x8 pfrag = __builtin_bit_cast(bf16x8, pu);
#pragma unroll
    for (int t = 0; t < 8; t++) {
      bf16x8 vf = ldb(VT + (size_t)(t * 16 + lo) * NTOK + kb0 + g * 8);
      o[t] = mfma16(pfrag, vf, o[t]);
    }
  }
  float linv[4];
#pragma unroll
  for (int r = 0; r < 4; r++) {
    float lr = __shfl(l, (lane & 48) + kl4 + r, 64);
    linv[r] = lr > 0.f ? 1.0f / lr : 0.0f;
  }
#pragma unroll
  for (int t = 0; t < 8; t++) {
#pragma unroll
    for (int r = 0; r < 4; r++) {
      int qn = q0 + kl4 + r;
      aout[((size_t)b * NTOK + qn) * (NH * DH) + h * DH + t * 16 + lo] = f2bf(o[t][r] * linv[r]);
    }
  }
}

// ---- out-proj (K=1024) + bias + residual + LayerNorm + SiLU + node_mask ----
__global__ __launch_bounds__(256) void k_gemm3(
    const unsigned short* __restrict__ aout, const unsigned short* __restrict__ wot,
    const float* __restrict__ x, const float* __restrict__ bo,
    const float* __restrict__ gamma, const float* __restrict__ beta,
    const void* __restrict__ nmask, const int* __restrict__ flagp,
    float* __restrict__ out) {
  int flag = *flagp;
  int lane = threadIdx.x & 63, w = threadIdx.x >> 6;
  int lo = lane & 15, g = lane >> 4;
  int rowb = blockIdx.x * 64 + w * 16;
  f32x4 acc[8] = {};
  const unsigned short* arow = aout + (size_t)(rowb + lo) * 1024 + g * 8;
  for (int ks = 0; ks < 32; ks++) {
    bf16x8 af = ldb(arow + 32 * ks);
#pragma unroll
    for (int t = 0; t < 8; t++) {
      bf16x8 bf = ldb(wot + (size_t)(t * 16 + lo) * 1024 + g * 8 + 32 * ks);
      acc[t] = mfma16(af, bf, acc[t]);
    }
  }
  float gv[8], bv[8], bov[8];
#pragma unroll
  for (int t = 0; t < 8; t++) {
    int col = t * 16 + lo;
    gv[t] = gamma[col]; bv[t] = beta[col]; bov[t] = bo[col];
  }
  float y[8][4];
#pragma unroll
  for (int t = 0; t < 8; t++) {
#pragma unroll
    for (int r = 0; r < 4; r++) {
      int row = rowb + 4 * g + r;
      y[t][r] = acc[t][r] + bov[t] + x[(size_t)row * 128 + t * 16 + lo];
    }
  }
#pragma unroll
  for (int r = 0; r < 4; r++) {
    int row = rowb + 4 * g + r;
    float s = 0.f;
#pragma unroll
    for (int t = 0; t < 8; t++) s += y[t][r];
    s += __shfl_xor(s, 1, 64); s += __shfl_xor(s, 2, 64);
    s += __shfl_xor(s, 4, 64); s += __shfl_xor(s, 8, 64);
    float mu = s * 0.0078125f;
    float vs = 0.f;
#pragma unroll
    for (int t = 0; t < 8; t++) { float d = y[t][r] - mu; vs += d * d; }
    vs += __shfl_xor(vs, 1, 64); vs += __shfl_xor(vs, 2, 64);
    vs += __shfl_xor(vs, 4, 64); vs += __shfl_xor(vs, 8, 64);
    float rstd = rsqrtf(vs * 0.0078125f + 1e-5f);
    float nm = mask_at(nmask, flag, row) ? 1.0f : 0.0f;
#pragma unroll
    for (int t = 0; t < 8; t++) {
      float z = (y[t][r] - mu) * rstd * gv[t] + bv[t];
      z = z / (1.0f + __expf(-z));          // SiLU
      out[(size_t)row * 128 + t * 16 + lo] = z * nm;
    }
  }
}

extern "C" void kernel_launch(void* const* d_in, const int* in_sizes, int n_in,
                              void* d_out, int out_size, void* d_ws, size_t ws_size,
                              hipStream_t stream) {
  (void)in_sizes; (void)n_in; (void)out_size;
  const float* x = (const float*)d_in[0];
  const void* amask = d_in[1];
  const void* nmask = d_in[2];
  const float* Wq = (const float*)d_in[3];
  const float* Wk = (const float*)d_in[4];
  const float* Wv = (const float*)d_in[5];
  const float* Wo = (const float*)d_in[6];
  const float* bo = (const float*)d_in[7];
  const float* gamma = (const float*)d_in[8];
  const float* beta = (const float*)d_in[9];
  float* out = (float*)d_out;
  char* ws = (char*)d_ws;

  constexpr size_t OFF_FLAG = 0;
  constexpr size_t OFF_XB   = 256;
  constexpr size_t OFF_WQT  = OFF_XB  + (size_t)8192 * 128 * 2;
  constexpr size_t OFF_WKT  = OFF_WQT + (size_t)1024 * 128 * 2;
  constexpr size_t OFF_WVT  = OFF_WKT + (size_t)1024 * 128 * 2;
  constexpr size_t OFF_WOT  = OFF_WVT + (size_t)1024 * 128 * 2;
  constexpr size_t OFF_BITS = OFF_WOT + (size_t)1024 * 128 * 2;
  constexpr size_t OFF_QB   = OFF_BITS + (size_t)NB * NTOK * NTOK / 8;
  constexpr size_t OFF_KB   = OFF_QB  + (size_t)NB * NH * NTOK * DH * 2;
  constexpr size_t OFF_VTB  = OFF_KB  + (size_t)NB * NH * NTOK * DH * 2;
  constexpr size_t OFF_AO   = OFF_VTB + (size_t)NB * NH * NTOK * DH * 2;
  constexpr size_t TOTAL    = OFF_AO  + (size_t)NB * NTOK * NH * DH * 2;
  if (ws_size < TOTAL) return;

  int* flag = (int*)(ws + OFF_FLAG);
  unsigned short* xb  = (unsigned short*)(ws + OFF_XB);
  unsigned short* wqt = (unsigned short*)(ws + OFF_WQT);
  unsigned short* wkt = (unsigned short*)(ws + OFF_WKT);
  unsigned short* wvt = (unsigned short*)(ws + OFF_WVT);
  unsigned short* wot = (unsigned short*)(ws + OFF_WOT);
  unsigned int* bits  = (unsigned int*)(ws + OFF_BITS);
  unsigned short* qb  = (unsigned short*)(ws + OFF_QB);
  unsigned short* kbf = (unsigned short*)(ws + OFF_KB);
  unsigned short* vtb = (unsigned short*)(ws + OFF_VTB);
  unsigned short* ao  = (unsigned short*)(ws + OFF_AO);

  k_detect<<<1, 256, 0, stream>>>((const unsigned int*)amask, flag);
  k_cvt_x<<<4096, 256, 0, stream>>>(x, xb, 8192 * 128);
  k_transpose_w<<<512, 256, 0, stream>>>(Wq, wqt, 128, 1024);
  k_transpose_w<<<512, 256, 0, stream>>>(Wk, wkt, 128, 1024);
  k_transpose_w<<<512, 256, 0, stream>>>(Wv, wvt, 128, 1024);
  k_transpose_w<<<512, 256, 0, stream>>>(Wo, wot, 1024, 128);
  k_pack_mask<<<65536, 256, 0, stream>>>(amask, flag, bits, NB * NTOK * NTOK);
  k_gemm_qkv<<<dim3(128, 8, 3), 256, 0, stream>>>(xb, wqt, wkt, wvt, qb, kbf, vtb);
  k_attn<<<1024, 256, 0, stream>>>(qb, kbf, vtb, bits, ao);
  k_gemm3<<<128, 256, 0, stream>>>(ao, wot, x, bo, gamma, beta, nmask, flag, out);
}

// Round 2
// 434.978 us; speedup vs baseline: 1.7432x; 1.7432x over previous
//
#include <hip/hip_runtime.h>

#define NTOK 2048
#define NB 4
#define NH 8
#define DH 128

typedef __bf16 bf16x8 __attribute__((ext_vector_type(8)));
typedef unsigned short u16x8 __attribute__((ext_vector_type(8)));
typedef float f32x4 __attribute__((ext_vector_type(4)));
typedef float f32x16 __attribute__((ext_vector_type(16)));
typedef unsigned int u32x4 __attribute__((ext_vector_type(4)));

__device__ __forceinline__ f32x4 mfma16(bf16x8 a, bf16x8 b, f32x4 c) {
  return __builtin_amdgcn_mfma_f32_16x16x32_bf16(a, b, c, 0, 0, 0);
}
__device__ __forceinline__ f32x16 mfma32(bf16x8 a, bf16x8 b, f32x16 c) {
  return __builtin_amdgcn_mfma_f32_32x32x16_bf16(a, b, c, 0, 0, 0);
}
__device__ __forceinline__ bf16x8 ldb(const unsigned short* p) {
  return __builtin_bit_cast(bf16x8, *(const u16x8*)p);
}
__device__ __forceinline__ unsigned short f2bf(float f) {
  unsigned int u = __builtin_bit_cast(unsigned int, f);
  u += 0x7fffu + ((u >> 16) & 1u);
  return (unsigned short)(u >> 16);
}
__device__ __forceinline__ unsigned int cvtpk(float lo, float hi) {
  unsigned int r;
  asm("v_cvt_pk_bf16_f32 %0, %1, %2" : "=v"(r) : "v"(lo), "v"(hi));
  return r;
}
// flag: 0 = int32, 1 = uint8, 2 = float32
__device__ __forceinline__ bool mask_at(const void* p, int flag, int idx) {
  if (flag == 1) return ((const unsigned char*)p)[idx] != 0;
  if (flag == 0) return ((const int*)p)[idx] != 0;
  return ((const float*)p)[idx] != 0.0f;
}

// ---- dtype detection: scan first 16384 dwords of attn_mask ----
__global__ void k_detect(const unsigned int* dw, int* flag) {
  __shared__ int su8, sf32;
  if (threadIdx.x == 0) { su8 = 0; sf32 = 0; }
  __syncthreads();
  int lu8 = 0, lf32 = 0;
  for (int i = threadIdx.x; i < 16384; i += blockDim.x) {
    unsigned int v = dw[i];
    if (v == 0x3f800000u) lf32 = 1;          // float 1.0
    else if (v != 0u && v != 1u) lu8 = 1;    // bytes set beyond byte0 -> u8 layout
  }
  if (lu8) atomicOr(&su8, 1);
  if (lf32) atomicOr(&sf32, 1);
  __syncthreads();
  if (threadIdx.x == 0) *flag = sf32 ? 2 : (su8 ? 1 : 0);
}

__global__ void k_cvt_x(const float* __restrict__ x, unsigned short* __restrict__ xb, int n) {
  int i = blockIdx.x * blockDim.x + threadIdx.x;
  if (i < n) xb[i] = f2bf(x[i]);
}

// w: [R][C] f32 -> wt: [C][R] bf16
__global__ void k_transpose_w(const float* __restrict__ w, unsigned short* __restrict__ wt, int R, int C) {
  int i = blockIdx.x * blockDim.x + threadIdx.x;
  if (i < R * C) {
    int c = i / R, r = i - c * R;
    wt[i] = f2bf(w[(size_t)r * C + c]);
  }
}

// pack attn_mask into bit array: bit j of word w = element w*32+j
__global__ void k_pack_mask(const void* __restrict__ am, const int* __restrict__ flagp,
                            unsigned int* __restrict__ bits, int n) {
  int flag = *flagp;
  int i = blockIdx.x * blockDim.x + threadIdx.x;
  bool v = (i < n) ? mask_at(am, flag, i) : false;
  unsigned long long bm = __ballot(v);
  int lane = threadIdx.x & 63;
  if (lane == 0) bits[i >> 5] = (unsigned int)bm;
  else if (lane == 32) bits[i >> 5] = (unsigned int)(bm >> 32);
}

// ---- QKV projection: [8192,128] @ [128,1024] per weight; K=128 in one pass ----
// Q is pre-scaled by 1/sqrt(DH) so attention skips the scale.
__global__ __launch_bounds__(256) void k_gemm_qkv(
    const unsigned short* __restrict__ xb, const unsigned short* __restrict__ wqt,
    const unsigned short* __restrict__ wkt, const unsigned short* __restrict__ wvt,
    unsigned short* __restrict__ qb, unsigned short* __restrict__ kbuf,
    unsigned short* __restrict__ vtb) {
  int which = blockIdx.z;
  const unsigned short* wt = which == 0 ? wqt : (which == 1 ? wkt : wvt);
  int lane = threadIdx.x & 63, w = threadIdx.x >> 6;
  int lo = lane & 15, g = lane >> 4;
  int rbase = blockIdx.x * 64 + w * 16;
  int colb = blockIdx.y * 128;
  bf16x8 af[4];
  const unsigned short* xrow = xb + (size_t)(rbase + lo) * 128 + g * 8;
#pragma unroll
  for (int s = 0; s < 4; s++) af[s] = ldb(xrow + 32 * s);
  f32x4 acc[8] = {};
#pragma unroll
  for (int c = 0; c < 8; c++) {
    const unsigned short* wrow = wt + (size_t)(colb + c * 16 + lo) * 128 + g * 8;
#pragma unroll
    for (int s = 0; s < 4; s++) acc[c] = mfma16(af[s], ldb(wrow + 32 * s), acc[c]);
  }
  float sc = (which == 0) ? 0.08838834764831845f : 1.0f;
#pragma unroll
  for (int c = 0; c < 8; c++) {
#pragma unroll
    for (int r = 0; r < 4; r++) {
      int row = rbase + 4 * g + r;            // D-layout: row=(lane>>4)*4+reg
      int col = colb + c * 16 + lo;           //           col=lane&15
      int b = row >> 11, n = row & (NTOK - 1);
      int h = col >> 7, d = col & 127;
      unsigned short val = f2bf(acc[c][r] * sc);
      size_t bh = (size_t)(b * NH + h);
      if (which == 2)      vtb[(bh * DH + d) * NTOK + n] = val;   // V transposed [bh][d][n]
      else if (which == 0) qb[(bh * NTOK + n) * DH + d] = val;
      else                 kbuf[(bh * NTOK + n) * DH + d] = val;
    }
  }
}

// ---- flash attention, 32x32 swapped QK^T, in-register softmax (lane-local keys) ----
// Per wave: QBLK=32 q-rows, KVBLK=32 keys/iter. S^T = mfma32(K, Q):
//   lane l owns q = l&31; reg r holds key (r&3)+8*(r>>2)+4*(l>>5).
// Softmax over keys = in-register fmax/sum tree + ONE shfl_xor(32) per reduce.
// Defer-max (THR=8, m0=0): rescale path ~never taken for N(0,1) scores.
__global__ __launch_bounds__(256) void k_attn32(
    const unsigned short* __restrict__ qb, const unsigned short* __restrict__ kbuf,
    const unsigned short* __restrict__ vtb, const unsigned int* __restrict__ mbits,
    unsigned short* __restrict__ aout) {
  int bid = blockIdx.x;              // 512 = 32 bh * 16 qchunks(128 rows)
  int bh = bid >> 4, qc = bid & 15;
  int b = bh >> 3, h = bh & 7;
  int lane = threadIdx.x & 63, w = threadIdx.x >> 6;
  int ql = lane & 31, hi = lane >> 5;
  int q0 = qc * 128 + w * 32;
  const unsigned short* Q = qb + (size_t)bh * NTOK * DH;
  const unsigned short* K = kbuf + (size_t)bh * NTOK * DH;
  const unsigned short* VT = vtb + (size_t)bh * NTOK * DH;

  bf16x8 qf[8];
  {
    const unsigned short* qrow = Q + (size_t)(q0 + ql) * DH + 8 * hi;
#pragma unroll
    for (int s = 0; s < 8; s++) qf[s] = ldb(qrow + 16 * s);
  }
  f32x16 o0 = {}, o1 = {}, o2 = {}, o3 = {};
  float m = 0.0f, l = 0.0f;
  const unsigned int* mrow = mbits + (size_t)b * (NTOK * NTOK / 32) + (size_t)(q0 + ql) * (NTOK / 32);

  for (int kb0 = 0; kb0 < NTOK; kb0 += 32) {
    unsigned int mw = mrow[kb0 >> 5] >> (4 * hi);
    // --- S^T = K . Q^T over d=128 (8 MFMA) ---
    f32x16 sT = {};
    const unsigned short* krow = K + (size_t)(kb0 + ql) * DH + 8 * hi;
#pragma unroll
    for (int s = 0; s < 8; s++) sT = mfma32(ldb(krow + 16 * s), qf[s], sT);
    // --- mask + in-register max over this lane's 16 keys ---
    float sv[16];
#pragma unroll
    for (int r = 0; r < 16; r++) {
      int cpos = (r & 3) + 8 * (r >> 2);     // key bit within mw (after >>4*hi)
      sv[r] = ((mw >> cpos) & 1u) ? sT[r] : -3.0e38f;
    }
    float mx01 = fmaxf(fmaxf(sv[0], sv[1]), fmaxf(sv[2], sv[3]));
    float mx23 = fmaxf(fmaxf(sv[4], sv[5]), fmaxf(sv[6], sv[7]));
    float mx45 = fmaxf(fmaxf(sv[8], sv[9]), fmaxf(sv[10], sv[11]));
    float mx67 = fmaxf(fmaxf(sv[12], sv[13]), fmaxf(sv[14], sv[15]));
    float pmax = fmaxf(fmaxf(mx01, mx23), fmaxf(mx45, mx67));
    float pj = fmaxf(pmax, __shfl_xor(pmax, 32, 64));
    if (__any(pj > m + 8.0f)) {              // rare rescale path (defer-max)
      float mnew = fmaxf(m, pj);
      float corr = __expf(m - mnew);
      l *= corr;
      float co[16];
#pragma unroll
      for (int r = 0; r < 16; r++) {
        int qr = (r & 3) + 8 * (r >> 2) + 4 * hi;
        co[r] = __shfl(corr, qr, 64);
      }
#pragma unroll
      for (int r = 0; r < 16; r++) { o0[r] *= co[r]; o1[r] *= co[r]; o2[r] *= co[r]; o3[r] *= co[r]; }
      m = mnew;
    }
    // --- P = exp(S - m), lane-local sum ---
    float p[16];
    float ps = 0.f;
#pragma unroll
    for (int r = 0; r < 16; r++) { p[r] = __expf(sv[r] - m); ps += p[r]; }
    l += ps;
    // --- pack to bf16 + exchange halves -> PV A-fragments ---
    unsigned int w8[8], pw8[8];
#pragma unroll
    for (int j = 0; j < 8; j++) w8[j] = cvtpk(p[2 * j], p[2 * j + 1]);
#pragma unroll
    for (int j = 0; j < 8; j++) pw8[j] = __shfl_xor((int)w8[j], 32, 64);
    u32x4 t0, t1;
    if (hi) {
      t0 = u32x4{pw8[2], pw8[3], w8[2], w8[3]};
      t1 = u32x4{pw8[6], pw8[7], w8[6], w8[7]};
    } else {
      t0 = u32x4{w8[0], w8[1], pw8[0], pw8[1]};
      t1 = u32x4{w8[4], w8[5], pw8[4], pw8[5]};
    }
    bf16x8 fk0 = __builtin_bit_cast(bf16x8, t0);
    bf16x8 fk1 = __builtin_bit_cast(bf16x8, t1);
    // --- PV: o[t] += P[q][k] * V[k][d], V from VT rows (contiguous in k) ---
    const unsigned short* vrow = VT + (size_t)ql * NTOK + kb0 + 8 * hi;
    o0 = mfma32(fk0, ldb(vrow), o0);
    o1 = mfma32(fk0, ldb(vrow + 32 * NTOK), o1);
    o2 = mfma32(fk0, ldb(vrow + 64 * NTOK), o2);
    o3 = mfma32(fk0, ldb(vrow + 96 * NTOK), o3);
    o0 = mfma32(fk1, ldb(vrow + 16), o0);
    o1 = mfma32(fk1, ldb(vrow + 32 * NTOK + 16), o1);
    o2 = mfma32(fk1, ldb(vrow + 64 * NTOK + 16), o2);
    o3 = mfma32(fk1, ldb(vrow + 96 * NTOK + 16), o3);
  }
  // --- finalize: joint l, per-row 1/l, store ---
  float lj = l + __shfl_xor(l, 32, 64);
  float linv = lj > 0.f ? 1.0f / lj : 0.0f;
  float li[16];
#pragma unroll
  for (int r = 0; r < 16; r++) {
    int qr = (r & 3) + 8 * (r >> 2) + 4 * hi;
    li[r] = __shfl(linv, qr, 64);
  }
  unsigned short* obase = aout + (size_t)b * NTOK * (NH * DH) + (size_t)h * DH + ql;
#pragma unroll
  for (int r = 0; r < 16; r++) {
    int qn = q0 + (r & 3) + 8 * (r >> 2) + 4 * hi;
    unsigned short* op = obase + (size_t)qn * (NH * DH);
    op[0]  = f2bf(o0[r] * li[r]);
    op[32] = f2bf(o1[r] * li[r]);
    op[64] = f2bf(o2[r] * li[r]);
    op[96] = f2bf(o3[r] * li[r]);
  }
}

// ---- out-proj (K=1024) + bias + residual + LayerNorm + SiLU + node_mask ----
__global__ __launch_bounds__(256) void k_gemm3(
    const unsigned short* __restrict__ aout, const unsigned short* __restrict__ wot,
    const float* __restrict__ x, const float* __restrict__ bo,
    const float* __restrict__ gamma, const float* __restrict__ beta,
    const void* __restrict__ nmask, const int* __restrict__ flagp,
    float* __restrict__ out) {
  int flag = *flagp;
  int lane = threadIdx.x & 63, w = threadIdx.x >> 6;
  int lo = lane & 15, g = lane >> 4;
  int rowb = blockIdx.x * 64 + w * 16;
  f32x4 acc[8] = {};
  const unsigned short* arow = aout + (size_t)(rowb + lo) * 1024 + g * 8;
  for (int ks = 0; ks < 32; ks++) {
    bf16x8 af = ldb(arow + 32 * ks);
#pragma unroll
    for (int t = 0; t < 8; t++) {
      bf16x8 bf = ldb(wot + (size_t)(t * 16 + lo) * 1024 + g * 8 + 32 * ks);
      acc[t] = mfma16(af, bf, acc[t]);
    }
  }
  float gv[8], bv[8], bov[8];
#pragma unroll
  for (int t = 0; t < 8; t++) {
    int col = t * 16 + lo;
    gv[t] = gamma[col]; bv[t] = beta[col]; bov[t] = bo[col];
  }
  float y[8][4];
#pragma unroll
  for (int t = 0; t < 8; t++) {
#pragma unroll
    for (int r = 0; r < 4; r++) {
      int row = rowb + 4 * g + r;
      y[t][r] = acc[t][r] + bov[t] + x[(size_t)row * 128 + t * 16 + lo];
    }
  }
#pragma unroll
  for (int r = 0; r < 4; r++) {
    int row = rowb + 4 * g + r;
    float s = 0.f;
#pragma unroll
    for (int t = 0; t < 8; t++) s += y[t][r];
    s += __shfl_xor(s, 1, 64); s += __shfl_xor(s, 2, 64);
    s += __shfl_xor(s, 4, 64); s += __shfl_xor(s, 8, 64);
    float mu = s * 0.0078125f;
    float vs = 0.f;
#pragma unroll
    for (int t = 0; t < 8; t++) { float d = y[t][r] - mu; vs += d * d; }
    vs += __shfl_xor(vs, 1, 64); vs += __shfl_xor(vs, 2, 64);
    vs += __shfl_xor(vs, 4, 64); vs += __shfl_xor(vs, 8, 64);
    float rstd = rsqrtf(vs * 0.0078125f + 1e-5f);
    float nm = mask_at(nmask, flag, row) ? 1.0f : 0.0f;
#pragma unroll
    for (int t = 0; t < 8; t++) {
      float z = (y[t][r] - mu) * rstd * gv[t] + bv[t];
      z = z / (1.0f + __expf(-z));          // SiLU
      out[(size_t)row * 128 + t * 16 + lo] = z * nm;
    }
  }
}

extern "C" void kernel_launch(void* const* d_in, const int* in_sizes, int n_in,
                              void* d_out, int out_size, void* d_ws, size_t ws_size,
                              hipStream_t stream) {
  (void)in_sizes; (void)n_in; (void)out_size;
  const float* x = (const float*)d_in[0];
  const void* amask = d_in[1];
  const void* nmask = d_in[2];
  const float* Wq = (const float*)d_in[3];
  const float* Wk = (const float*)d_in[4];
  const float* Wv = (const float*)d_in[5];
  const float* Wo = (const float*)d_in[6];
  const float* bo = (const float*)d_in[7];
  const float* gamma = (const float*)d_in[8];
  const float* beta = (const float*)d_in[9];
  float* out = (float*)d_out;
  char* ws = (char*)d_ws;

  constexpr size_t OFF_FLAG = 0;
  constexpr size_t OFF_XB   = 256;
  constexpr size_t OFF_WQT  = OFF_XB  + (size_t)8192 * 128 * 2;
  constexpr size_t OFF_WKT  = OFF_WQT + (size_t)1024 * 128 * 2;
  constexpr size_t OFF_WVT  = OFF_WKT + (size_t)1024 * 128 * 2;
  constexpr size_t OFF_WOT  = OFF_WVT + (size_t)1024 * 128 * 2;
  constexpr size_t OFF_BITS = OFF_WOT + (size_t)1024 * 128 * 2;
  constexpr size_t OFF_QB   = OFF_BITS + (size_t)NB * NTOK * NTOK / 8;
  constexpr size_t OFF_KB   = OFF_QB  + (size_t)NB * NH * NTOK * DH * 2;
  constexpr size_t OFF_VTB  = OFF_KB  + (size_t)NB * NH * NTOK * DH * 2;
  constexpr size_t OFF_AO   = OFF_VTB + (size_t)NB * NH * NTOK * DH * 2;
  constexpr size_t TOTAL    = OFF_AO  + (size_t)NB * NTOK * NH * DH * 2;
  if (ws_size < TOTAL) return;

  int* flag = (int*)(ws + OFF_FLAG);
  unsigned short* xb  = (unsigned short*)(ws + OFF_XB);
  unsigned short* wqt = (unsigned short*)(ws + OFF_WQT);
  unsigned short* wkt = (unsigned short*)(ws + OFF_WKT);
  unsigned short* wvt = (unsigned short*)(ws + OFF_WVT);
  unsigned short* wot = (unsigned short*)(ws + OFF_WOT);
  unsigned int* bits  = (unsigned int*)(ws + OFF_BITS);
  unsigned short* qb  = (unsigned short*)(ws + OFF_QB);
  unsigned short* kbf = (unsigned short*)(ws + OFF_KB);
  unsigned short* vtb = (unsigned short*)(ws + OFF_VTB);
  unsigned short* ao  = (unsigned short*)(ws + OFF_AO);

  k_detect<<<1, 256, 0, stream>>>((const unsigned int*)amask, flag);
  k_cvt_x<<<4096, 256, 0, stream>>>(x, xb, 8192 * 128);
  k_transpose_w<<<512, 256, 0, stream>>>(Wq, wqt, 128, 1024);
  k_transpose_w<<<512, 256, 0, stream>>>(Wk, wkt, 128, 1024);
  k_transpose_w<<<512, 256, 0, stream>>>(Wv, wvt, 128, 1024);
  k_transpose_w<<<512, 256, 0, stream>>>(Wo, wot, 1024, 128);
  k_pack_mask<<<65536, 256, 0, stream>>>(amask, flag, bits, NB * NTOK * NTOK);
  k_gemm_qkv<<<dim3(128, 8, 3), 256, 0, stream>>>(xb, wqt, wkt, wvt, qb, kbf, vtb);
  k_attn32<<<512, 256, 0, stream>>>(qb, kbf, vtb, bits, ao);
  k_gemm3<<<128, 256, 0, stream>>>(ao, wot, x, bo, gamma, beta, nmask, flag, out);
}

// Round 3
// 271.374 us; speedup vs baseline: 2.7942x; 1.6029x over previous
//
#include <hip/hip_runtime.h>

#define NTOK 2048
#define NB 4
#define NH 8
#define DH 128

typedef __bf16 bf16x8 __attribute__((ext_vector_type(8)));
typedef unsigned short u16x8 __attribute__((ext_vector_type(8)));
typedef float f32x4 __attribute__((ext_vector_type(4)));
typedef float f32x16 __attribute__((ext_vector_type(16)));
typedef unsigned int u32x4 __attribute__((ext_vector_type(4)));

__device__ __forceinline__ f32x4 mfma16(bf16x8 a, bf16x8 b, f32x4 c) {
  return __builtin_amdgcn_mfma_f32_16x16x32_bf16(a, b, c, 0, 0, 0);
}
__device__ __forceinline__ f32x16 mfma32(bf16x8 a, bf16x8 b, f32x16 c) {
  return __builtin_amdgcn_mfma_f32_32x32x16_bf16(a, b, c, 0, 0, 0);
}
__device__ __forceinline__ bf16x8 ldb(const unsigned short* p) {
  return __builtin_bit_cast(bf16x8, *(const u16x8*)p);
}
__device__ __forceinline__ bf16x8 ldsb(const char* p) {
  return __builtin_bit_cast(bf16x8, *(const u16x8*)p);
}
__device__ __forceinline__ unsigned short f2bf(float f) {
  unsigned int u = __builtin_bit_cast(unsigned int, f);
  u += 0x7fffu + ((u >> 16) & 1u);
  return (unsigned short)(u >> 16);
}
__device__ __forceinline__ unsigned int cvtpk(float lo, float hi) {
  unsigned int r;
  asm("v_cvt_pk_bf16_f32 %0, %1, %2" : "=v"(r) : "v"(lo), "v"(hi));
  return r;
}
// async global->LDS, 16B per lane; LDS dest = base (wave-uniform) + lane*16
#define GLL(gsrc, ldst) __builtin_amdgcn_global_load_lds(                      \
    (const __attribute__((address_space(1))) void*)(gsrc),                     \
    (__attribute__((address_space(3))) void*)(ldst), 16, 0, 0)

// flag: 0 = int32, 1 = uint8, 2 = float32
__device__ __forceinline__ bool mask_at(const void* p, int flag, int idx) {
  if (flag == 1) return ((const unsigned char*)p)[idx] != 0;
  if (flag == 0) return ((const int*)p)[idx] != 0;
  return ((const float*)p)[idx] != 0.0f;
}

// ---- dtype detection: scan first 16384 dwords of attn_mask ----
__global__ void k_detect(const unsigned int* dw, int* flag) {
  __shared__ int su8, sf32;
  if (threadIdx.x == 0) { su8 = 0; sf32 = 0; }
  __syncthreads();
  int lu8 = 0, lf32 = 0;
  for (int i = threadIdx.x; i < 16384; i += blockDim.x) {
    unsigned int v = dw[i];
    if (v == 0x3f800000u) lf32 = 1;          // float 1.0
    else if (v != 0u && v != 1u) lu8 = 1;    // bytes set beyond byte0 -> u8 layout
  }
  if (lu8) atomicOr(&su8, 1);
  if (lf32) atomicOr(&sf32, 1);
  __syncthreads();
  if (threadIdx.x == 0) *flag = sf32 ? 2 : (su8 ? 1 : 0);
}

__global__ void k_cvt_x(const float* __restrict__ x, unsigned short* __restrict__ xb, int n) {
  int i = blockIdx.x * blockDim.x + threadIdx.x;
  if (i < n) xb[i] = f2bf(x[i]);
}

// w: [R][C] f32 -> wt: [C][R] bf16
__global__ void k_transpose_w(const float* __restrict__ w, unsigned short* __restrict__ wt, int R, int C) {
  int i = blockIdx.x * blockDim.x + threadIdx.x;
  if (i < R * C) {
    int c = i / R, r = i - c * R;
    wt[i] = f2bf(w[(size_t)r * C + c]);
  }
}

// pack attn_mask into bit array: bit j of word w = element w*32+j
__global__ void k_pack_mask(const void* __restrict__ am, const int* __restrict__ flagp,
                            unsigned int* __restrict__ bits, int n) {
  int flag = *flagp;
  int i = blockIdx.x * blockDim.x + threadIdx.x;
  bool v = (i < n) ? mask_at(am, flag, i) : false;
  unsigned long long bm = __ballot(v);
  int lane = threadIdx.x & 63;
  if (lane == 0) bits[i >> 5] = (unsigned int)bm;
  else if (lane == 32) bits[i >> 5] = (unsigned int)(bm >> 32);
}

// ---- QKV projection: [8192,128] @ [128,1024] per weight; K=128 in one pass ----
// Q pre-scaled by 1/sqrt(DH). V written transposed [bh][d][n] via LDS (coalesced).
__global__ __launch_bounds__(256) void k_gemm_qkv(
    const unsigned short* __restrict__ xb, const unsigned short* __restrict__ wqt,
    const unsigned short* __restrict__ wkt, const unsigned short* __restrict__ wvt,
    unsigned short* __restrict__ qb, unsigned short* __restrict__ kbuf,
    unsigned short* __restrict__ vtb) {
  __shared__ unsigned short vt_lds[8192];    // [d 128][n 64] swizzled, 16KB
  int which = blockIdx.z;
  const unsigned short* wt = which == 0 ? wqt : (which == 1 ? wkt : wvt);
  int lane = threadIdx.x & 63, w = threadIdx.x >> 6;
  int lo = lane & 15, g = lane >> 4;
  int rbase = blockIdx.x * 64 + w * 16;
  int colb = blockIdx.y * 128;
  bf16x8 af[4];
  const unsigned short* xrow = xb + (size_t)(rbase + lo) * 128 + g * 8;
#pragma unroll
  for (int s = 0; s < 4; s++) af[s] = ldb(xrow + 32 * s);
  f32x4 acc[8] = {};
#pragma unroll
  for (int c = 0; c < 8; c++) {
    const unsigned short* wrow = wt + (size_t)(colb + c * 16 + lo) * 128 + g * 8;
#pragma unroll
    for (int s = 0; s < 4; s++) acc[c] = mfma16(af[s], ldb(wrow + 32 * s), acc[c]);
  }
  if (which != 2) {
    float sc = (which == 0) ? 0.08838834764831845f : 1.0f;
#pragma unroll
    for (int c = 0; c < 8; c++) {
#pragma unroll
      for (int r = 0; r < 4; r++) {
        int row = rbase + 4 * g + r;          // D-layout: row=(lane>>4)*4+reg
        int col = colb + c * 16 + lo;         //           col=lane&15
        int b = row >> 11, n = row & (NTOK - 1);
        int h = col >> 7, d = col & 127;
        unsigned short val = f2bf(acc[c][r] * sc);
        size_t bh = (size_t)(b * NH + h);
        if (which == 0) qb[(bh * NTOK + n) * DH + d] = val;
        else            kbuf[(bh * NTOK + n) * DH + d] = val;
      }
    }
    return;
  }
  // V: transpose in LDS, write [d][n] coalesced
#pragma unroll
  for (int c = 0; c < 8; c++) {
#pragma unroll
    for (int r = 0; r < 4; r++) {
      int nl = w * 16 + 4 * g + r;
      int d = c * 16 + lo;
      int boff = d * 128 + ((nl * 2) ^ ((d & 7) << 4));
      *(unsigned short*)((char*)vt_lds + boff) = f2bf(acc[c][r]);
    }
  }
  __syncthreads();
  int t = threadIdx.x;
  int d = t >> 1, half = t & 1;
  int bb = (blockIdx.x * 64) >> 11;
  int n0 = (blockIdx.x * 64) & (NTOK - 1);
  size_t bh = (size_t)(bb * NH + blockIdx.y);
  unsigned short* dst = vtb + (bh * DH + d) * NTOK + n0 + half * 32;
  const char* srcb = (const char*)vt_lds + d * 128;
#pragma unroll
  for (int s = 0; s < 4; s++) {
    int lb = (half * 64 + s * 16) ^ ((d & 7) << 4);
    *(u16x8*)(dst + s * 8) = *(const u16x8*)(srcb + lb);
  }
}

// ---- flash attention, KVBLK=64, LDS-staged K/V double-buffered ----
// K tile [64][256B], V tile [128][128B], both XOR-swizzled byte^=((row&7)<<4).
// Staged via global_load_lds (linear LDS dest, pre-swizzled global source).
// 2-phase schedule: STAGE(next) -> compute(cur) -> __syncthreads (drains vmcnt).
__device__ __forceinline__ void stage64(const char* Kg, const char* Vg,
                                        char* kl, char* vl, int w, int lane) {
#pragma unroll
  for (int s = 0; s < 4; s++) {
    int a = s * 4096 + w * 1024 + lane * 16;
    int r = a >> 8;
    int cb = (a & 255) ^ ((r & 7) << 4);
    GLL(Kg + r * 256 + cb, kl + s * 4096 + w * 1024);
  }
#pragma unroll
  for (int s = 0; s < 4; s++) {
    int a = s * 4096 + w * 1024 + lane * 16;
    int r = a >> 7;
    int cb = (a & 127) ^ ((r & 7) << 4);
    GLL(Vg + (size_t)r * (NTOK * 2) + cb, vl + s * 4096 + w * 1024);
  }
}

__global__ __launch_bounds__(256, 2) void k_attn64(
    const unsigned short* __restrict__ qb, const unsigned short* __restrict__ kbuf,
    const unsigned short* __restrict__ vtb, const unsigned int* __restrict__ mbits,
    unsigned short* __restrict__ aout) {
  __shared__ char smem[65536];
  int bid = blockIdx.x;
  // XCD swizzle: bid&7 = b*2+(h>>2) -> each XCD owns 4 heads of one batch
  int low3 = bid & 7, mid2 = (bid >> 3) & 3, qc = bid >> 5;
  int b = low3 >> 1, h = ((low3 & 1) << 2) | mid2;
  int bh = b * 8 + h;
  int lane = threadIdx.x & 63, w = threadIdx.x >> 6;
  int ql = lane & 31, hi = lane >> 5;
  int q0 = qc * 128 + w * 32;
  const char* Kbase = (const char*)(kbuf + (size_t)bh * NTOK * DH);
  const char* Vbase = (const char*)(vtb + (size_t)bh * NTOK * DH);

  bf16x8 qf[8];
  {
    const unsigned short* qrow = qb + (size_t)bh * NTOK * DH + (size_t)(q0 + ql) * DH + 8 * hi;
#pragma unroll
    for (int s = 0; s < 8; s++) qf[s] = ldb(qrow + 16 * s);
  }
  const uint2* mrow = (const uint2*)(mbits + (size_t)b * (NTOK * NTOK / 32) + (size_t)(q0 + ql) * (NTOK / 32));

  f32x16 o0 = {}, o1 = {}, o2 = {}, o3 = {};
  float m = 0.0f, l = 0.0f;
  char* kl = smem;
  char* vl = smem + 32768;
  int xk = (ql & 7) << 4;

  stage64(Kbase, Vbase, kl, vl, w, lane);
  __syncthreads();

  for (int kt = 0; kt < NTOK / 64; kt++) {
    int cur = kt & 1;
    const char* kc = kl + cur * 16384;
    const char* vc = vl + cur * 16384;
    if (kt + 1 < NTOK / 64)
      stage64(Kbase + (size_t)(kt + 1) * 16384, Vbase + (size_t)(kt + 1) * 128,
              kl + (1 - cur) * 16384, vl + (1 - cur) * 16384, w, lane);
    uint2 mm = mrow[kt];
    unsigned int mw0 = mm.x >> (4 * hi), mw1 = mm.y >> (4 * hi);
    // --- S^T = K . Q^T, two 32-key halves (2x MFMA ILP) ---
    f32x16 sT0 = {}, sT1 = {};
    const char* kr0 = kc + ql * 256;
    const char* kr1 = kc + (32 + ql) * 256;
    __builtin_amdgcn_s_setprio(1);
#pragma unroll
    for (int s = 0; s < 8; s++) {
      int cb = (32 * s + 16 * hi) ^ xk;
      sT0 = mfma32(ldsb(kr0 + cb), qf[s], sT0);
      sT1 = mfma32(ldsb(kr1 + cb), qf[s], sT1);
    }
    __builtin_amdgcn_s_setprio(0);
    // --- mask + in-register softmax over 32 lane-local keys ---
    float sv0[16], sv1[16];
#pragma unroll
    for (int r = 0; r < 16; r++) {
      int cpos = (r & 3) + 8 * (r >> 2);
      sv0[r] = ((mw0 >> cpos) & 1u) ? sT0[r] : -3.0e38f;
      sv1[r] = ((mw1 >> cpos) & 1u) ? sT1[r] : -3.0e38f;
    }
    float mx = -3.0e38f;
#pragma unroll
    for (int r = 0; r < 16; r++) mx = fmaxf(mx, fmaxf(sv0[r], sv1[r]));
    float pj = fmaxf(mx, __shfl_xor(mx, 32, 64));
    if (__any(pj > m + 8.0f)) {              // rare rescale (defer-max, THR=8)
      float mnew = fmaxf(m, pj);
      float corr = __expf(m - mnew);
      l *= corr;
      float co[16];
#pragma unroll
      for (int r = 0; r < 16; r++) {
        int qr = (r & 3) + 8 * (r >> 2) + 4 * hi;
        co[r] = __shfl(corr, qr, 64);
      }
#pragma unroll
      for (int r = 0; r < 16; r++) { o0[r] *= co[r]; o1[r] *= co[r]; o2[r] *= co[r]; o3[r] *= co[r]; }
      m = mnew;
    }
    float ps = 0.f;
#pragma unroll
    for (int r = 0; r < 16; r++) { sv0[r] = __expf(sv0[r] - m); ps += sv0[r]; }
#pragma unroll
    for (int r = 0; r < 16; r++) { sv1[r] = __expf(sv1[r] - m); ps += sv1[r]; }
    l += ps;
    // --- pack bf16 + half-exchange -> PV A-fragments ---
    unsigned int w8a[8], w8b[8], pa[8], pb[8];
#pragma unroll
    for (int j = 0; j < 8; j++) {
      w8a[j] = cvtpk(sv0[2 * j], sv0[2 * j + 1]);
      w8b[j] = cvtpk(sv1[2 * j], sv1[2 * j + 1]);
    }
#pragma unroll
    for (int j = 0; j < 8; j++) {
      pa[j] = __shfl_xor((int)w8a[j], 32, 64);
      pb[j] = __shfl_xor((int)w8b[j], 32, 64);
    }
    u32x4 ta0, ta1, tb0, tb1;
    if (hi) {
      ta0 = u32x4{pa[2], pa[3], w8a[2], w8a[3]};
      ta1 = u32x4{pa[6], pa[7], w8a[6], w8a[7]};
      tb0 = u32x4{pb[2], pb[3], w8b[2], w8b[3]};
      tb1 = u32x4{pb[6], pb[7], w8b[6], w8b[7]};
    } else {
      ta0 = u32x4{w8a[0], w8a[1], pa[0], pa[1]};
      ta1 = u32x4{w8a[4], w8a[5], pa[4], pa[5]};
      tb0 = u32x4{w8b[0], w8b[1], pb[0], pb[1]};
      tb1 = u32x4{w8b[4], w8b[5], pb[4], pb[5]};
    }
    bf16x8 fkA0 = __builtin_bit_cast(bf16x8, ta0);
    bf16x8 fkA1 = __builtin_bit_cast(bf16x8, ta1);
    bf16x8 fkB0 = __builtin_bit_cast(bf16x8, tb0);
    bf16x8 fkB1 = __builtin_bit_cast(bf16x8, tb1);
    // --- PV from swizzled LDS V tile ---
    __builtin_amdgcn_s_setprio(1);
    {
      const char* vr0 = vc + (ql + 0) * 128;
      const char* vr1 = vc + (ql + 32) * 128;
      const char* vr2 = vc + (ql + 64) * 128;
      const char* vr3 = vc + (ql + 96) * 128;
      int c0 = (16 * hi) ^ xk, c1 = (32 + 16 * hi) ^ xk;
      int c2 = (64 + 16 * hi) ^ xk, c3 = (96 + 16 * hi) ^ xk;
      o0 = mfma32(fkA0, ldsb(vr0 + c0), o0);
      o1 = mfma32(fkA0, ldsb(vr1 + c0), o1);
      o2 = mfma32(fkA0, ldsb(vr2 + c0), o2);
      o3 = mfma32(fkA0, ldsb(vr3 + c0), o3);
      o0 = mfma32(fkA1, ldsb(vr0 + c1), o0);
      o1 = mfma32(fkA1, ldsb(vr1 + c1), o1);
      o2 = mfma32(fkA1, ldsb(vr2 + c1), o2);
      o3 = mfma32(fkA1, ldsb(vr3 + c1), o3);
      o0 = mfma32(fkB0, ldsb(vr0 + c2), o0);
      o1 = mfma32(fkB0, ldsb(vr1 + c2), o1);
      o2 = mfma32(fkB0, ldsb(vr2 + c2), o2);
      o3 = mfma32(fkB0, ldsb(vr3 + c2), o3);
      o0 = mfma32(fkB1, ldsb(vr0 + c3), o0);
      o1 = mfma32(fkB1, ldsb(vr1 + c3), o1);
      o2 = mfma32(fkB1, ldsb(vr2 + c3), o2);
      o3 = mfma32(fkB1, ldsb(vr3 + c3), o3);
    }
    __builtin_amdgcn_s_setprio(0);
    __syncthreads();
  }
  // --- finalize ---
  float lj = l + __shfl_xor(l, 32, 64);
  float linv = lj > 0.f ? 1.0f / lj : 0.0f;
  float li[16];
#pragma unroll
  for (int r = 0; r < 16; r++) {
    int qr = (r & 3) + 8 * (r >> 2) + 4 * hi;
    li[r] = __shfl(linv, qr, 64);
  }
  unsigned short* obase = aout + (size_t)b * NTOK * (NH * DH) + (size_t)h * DH + ql;
#pragma unroll
  for (int r = 0; r < 16; r++) {
    int qn = q0 + (r & 3) + 8 * (r >> 2) + 4 * hi;
    unsigned short* op = obase + (size_t)qn * (NH * DH);
    op[0]  = f2bf(o0[r] * li[r]);
    op[32] = f2bf(o1[r] * li[r]);
    op[64] = f2bf(o2[r] * li[r]);
    op[96] = f2bf(o3[r] * li[r]);
  }
}

// ---- out-proj (K=1024) + bias + residual + LayerNorm + SiLU + node_mask ----
__global__ __launch_bounds__(256) void k_gemm3(
    const unsigned short* __restrict__ aout, const unsigned short* __restrict__ wot,
    const float* __restrict__ x, const float* __restrict__ bo,
    const float* __restrict__ gamma, const float* __restrict__ beta,
    const void* __restrict__ nmask, const int* __restrict__ flagp,
    float* __restrict__ out) {
  int flag = *flagp;
  int lane = threadIdx.x & 63, w = threadIdx.x >> 6;
  int lo = lane & 15, g = lane >> 4;
  int rowb = blockIdx.x * 64 + w * 16;
  f32x4 acc[8] = {};
  const unsigned short* arow = aout + (size_t)(rowb + lo) * 1024 + g * 8;
  for (int ks = 0; ks < 32; ks++) {
    bf16x8 af = ldb(arow + 32 * ks);
#pragma unroll
    for (int t = 0; t < 8; t++) {
      bf16x8 bf = ldb(wot + (size_t)(t * 16 + lo) * 1024 + g * 8 + 32 * ks);
      acc[t] = mfma16(af, bf, acc[t]);
    }
  }
  float gv[8], bv[8], bov[8];
#pragma unroll
  for (int t = 0; t < 8; t++) {
    int col = t * 16 + lo;
    gv[t] = gamma[col]; bv[t] = beta[col]; bov[t] = bo[col];
  }
  float y[8][4];
#pragma unroll
  for (int t = 0; t < 8; t++) {
#pragma unroll
    for (int r = 0; r < 4; r++) {
      int row = rowb + 4 * g + r;
      y[t][r] = acc[t][r] + bov[t] + x[(size_t)row * 128 + t * 16 + lo];
    }
  }
#pragma unroll
  for (int r = 0; r < 4; r++) {
    int row = rowb + 4 * g + r;
    float s = 0.f;
#pragma unroll
    for (int t = 0; t < 8; t++) s += y[t][r];
    s += __shfl_xor(s, 1, 64); s += __shfl_xor(s, 2, 64);
    s += __shfl_xor(s, 4, 64); s += __shfl_xor(s, 8, 64);
    float mu = s * 0.0078125f;
    float vs = 0.f;
#pragma unroll
    for (int t = 0; t < 8; t++) { float d = y[t][r] - mu; vs += d * d; }
    vs += __shfl_xor(vs, 1, 64); vs += __shfl_xor(vs, 2, 64);
    vs += __shfl_xor(vs, 4, 64); vs += __shfl_xor(vs, 8, 64);
    float rstd = rsqrtf(vs * 0.0078125f + 1e-5f);
    float nm = mask_at(nmask, flag, row) ? 1.0f : 0.0f;
#pragma unroll
    for (int t = 0; t < 8; t++) {
      float z = (y[t][r] - mu) * rstd * gv[t] + bv[t];
      z = z / (1.0f + __expf(-z));          // SiLU
      out[(size_t)row * 128 + t * 16 + lo] = z * nm;
    }
  }
}

extern "C" void kernel_launch(void* const* d_in, const int* in_sizes, int n_in,
                              void* d_out, int out_size, void* d_ws, size_t ws_size,
                              hipStream_t stream) {
  (void)in_sizes; (void)n_in; (void)out_size;
  const float* x = (const float*)d_in[0];
  const void* amask = d_in[1];
  const void* nmask = d_in[2];
  const float* Wq = (const float*)d_in[3];
  const float* Wk = (const float*)d_in[4];
  const float* Wv = (const float*)d_in[5];
  const float* Wo = (const float*)d_in[6];
  const float* bo = (const float*)d_in[7];
  const float* gamma = (const float*)d_in[8];
  const float* beta = (const float*)d_in[9];
  float* out = (float*)d_out;
  char* ws = (char*)d_ws;

  constexpr size_t OFF_FLAG = 0;
  constexpr size_t OFF_XB   = 256;
  constexpr size_t OFF_WQT  = OFF_XB  + (size_t)8192 * 128 * 2;
  constexpr size_t OFF_WKT  = OFF_WQT + (size_t)1024 * 128 * 2;
  constexpr size_t OFF_WVT  = OFF_WKT + (size_t)1024 * 128 * 2;
  constexpr size_t OFF_WOT  = OFF_WVT + (size_t)1024 * 128 * 2;
  constexpr size_t OFF_BITS = OFF_WOT + (size_t)1024 * 128 * 2;
  constexpr size_t OFF_QB   = OFF_BITS + (size_t)NB * NTOK * NTOK / 8;
  constexpr size_t OFF_KB   = OFF_QB  + (size_t)NB * NH * NTOK * DH * 2;
  constexpr size_t OFF_VTB  = OFF_KB  + (size_t)NB * NH * NTOK * DH * 2;
  constexpr size_t OFF_AO   = OFF_VTB + (size_t)NB * NH * NTOK * DH * 2;
  constexpr size_t TOTAL    = OFF_AO  + (size_t)NB * NTOK * NH * DH * 2;
  if (ws_size < TOTAL) return;

  int* flag = (int*)(ws + OFF_FLAG);
  unsigned short* xb  = (unsigned short*)(ws + OFF_XB);
  unsigned short* wqt = (unsigned short*)(ws + OFF_WQT);
  unsigned short* wkt = (unsigned short*)(ws + OFF_WKT);
  unsigned short* wvt = (unsigned short*)(ws + OFF_WVT);
  unsigned short* wot = (unsigned short*)(ws + OFF_WOT);
  unsigned int* bits  = (unsigned int*)(ws + OFF_BITS);
  unsigned short* qb  = (unsigned short*)(ws + OFF_QB);
  unsigned short* kbf = (unsigned short*)(ws + OFF_KB);
  unsigned short* vtb = (unsigned short*)(ws + OFF_VTB);
  unsigned short* ao  = (unsigned short*)(ws + OFF_AO);

  k_detect<<<1, 256, 0, stream>>>((const unsigned int*)amask, flag);
  k_cvt_x<<<4096, 256, 0, stream>>>(x, xb, 8192 * 128);
  k_transpose_w<<<512, 256, 0, stream>>>(Wq, wqt, 128, 1024);
  k_transpose_w<<<512, 256, 0, stream>>>(Wk, wkt, 128, 1024);
  k_transpose_w<<<512, 256, 0, stream>>>(Wv, wvt, 128, 1024);
  k_transpose_w<<<512, 256, 0, stream>>>(Wo, wot, 1024, 128);
  k_pack_mask<<<65536, 256, 0, stream>>>(amask, flag, bits, NB * NTOK * NTOK);
  k_gemm_qkv<<<dim3(128, 8, 3), 256, 0, stream>>>(xb, wqt, wkt, wvt, qb, kbf, vtb);
  k_attn64<<<512, 256, 0, stream>>>(qb, kbf, vtb, bits, ao);
  k_gemm3<<<128, 256, 0, stream>>>(ao, wot, x, bo, gamma, beta, nmask, flag, out);
}

// Round 4
// 229.058 us; speedup vs baseline: 3.3104x; 1.1847x over previous
//
#include <hip/hip_runtime.h>

#define NTOK 2048
#define NB 4
#define NH 8
#define DH 128

typedef __bf16 bf16x8 __attribute__((ext_vector_type(8)));
typedef unsigned short u16x8 __attribute__((ext_vector_type(8)));
typedef float f32x4 __attribute__((ext_vector_type(4)));
typedef float f32x16 __attribute__((ext_vector_type(16)));
typedef unsigned int u32x4 __attribute__((ext_vector_type(4)));

__device__ __forceinline__ f32x4 mfma16(bf16x8 a, bf16x8 b, f32x4 c) {
  return __builtin_amdgcn_mfma_f32_16x16x32_bf16(a, b, c, 0, 0, 0);
}
__device__ __forceinline__ f32x16 mfma32(bf16x8 a, bf16x8 b, f32x16 c) {
  return __builtin_amdgcn_mfma_f32_32x32x16_bf16(a, b, c, 0, 0, 0);
}
__device__ __forceinline__ bf16x8 ldb(const unsigned short* p) {
  return __builtin_bit_cast(bf16x8, *(const u16x8*)p);
}
__device__ __forceinline__ bf16x8 ldsb(const char* p) {
  return __builtin_bit_cast(bf16x8, *(const u16x8*)p);
}
__device__ __forceinline__ unsigned short f2bf(float f) {
  unsigned int u = __builtin_bit_cast(unsigned int, f);
  u += 0x7fffu + ((u >> 16) & 1u);
  return (unsigned short)(u >> 16);
}
__device__ __forceinline__ unsigned int cvtpk(float lo, float hi) {
  unsigned int r;
  asm("v_cvt_pk_bf16_f32 %0, %1, %2" : "=v"(r) : "v"(lo), "v"(hi));
  return r;
}
#if __has_builtin(__builtin_amdgcn_exp2f)
__device__ __forceinline__ float exp2a(float x) { return __builtin_amdgcn_exp2f(x); }
#else
__device__ __forceinline__ float exp2a(float x) { return __expf(x * 0.6931471805599453f); }
#endif
// async global->LDS, 16B per lane; LDS dest = wave-uniform base + lane*16
#define GLL(gsrc, ldst) __builtin_amdgcn_global_load_lds(                      \
    (const __attribute__((address_space(1))) void*)(gsrc),                     \
    (__attribute__((address_space(3))) void*)(ldst), 16, 0, 0)

// flag: 0 = int32, 1 = uint8, 2 = float32 (int-compare works for 0/1.0f too)
__device__ __forceinline__ bool mask_at(const void* p, int flag, int idx) {
  if (flag == 1) return ((const unsigned char*)p)[idx] != 0;
  return ((const int*)p)[idx] != 0;
}

// ---- prep: detect mask dtype + cvt x to bf16 + transpose weights ----
__global__ __launch_bounds__(256) void k_prep(
    const float* __restrict__ x, const float* __restrict__ Wq,
    const float* __restrict__ Wk, const float* __restrict__ Wv,
    const float* __restrict__ Wo, const unsigned int* __restrict__ amdw,
    unsigned short* __restrict__ xb, unsigned short* __restrict__ wqt,
    unsigned short* __restrict__ wkt, unsigned short* __restrict__ wvt,
    unsigned short* __restrict__ wot, int* __restrict__ flag) {
  int bid = blockIdx.x, tid = threadIdx.x;
  if (bid == 0) {
    // dtype detect over first 64KB of attn_mask
    __shared__ int su8, sf32;
    if (tid == 0) { su8 = 0; sf32 = 0; }
    __syncthreads();
    const uint4* dw4 = (const uint4*)amdw;
    int lu8 = 0, lf32 = 0;
#pragma unroll
    for (int j = 0; j < 16; j++) {
      uint4 q = dw4[tid + j * 256];
      unsigned int vv[4] = {q.x, q.y, q.z, q.w};
#pragma unroll
      for (int e = 0; e < 4; e++) {
        unsigned int v = vv[e];
        if (v == 0x3f800000u) lf32 = 1;
        else if (v != 0u && v != 1u) lu8 = 1;
      }
    }
    if (lu8) atomicOr(&su8, 1);
    if (lf32) atomicOr(&sf32, 1);
    __syncthreads();
    if (tid == 0) *flag = sf32 ? 2 : (su8 ? 1 : 0);
    return;
  }
  if (bid < 513) {            // x -> bf16, 8 elems/thread
    int base = (bid - 1) * 2048 + tid * 8;
    const float4* xf = (const float4*)(x + base);
    float4 a = xf[0], b = xf[1];
    u16x8 o;
    o[0] = f2bf(a.x); o[1] = f2bf(a.y); o[2] = f2bf(a.z); o[3] = f2bf(a.w);
    o[4] = f2bf(b.x); o[5] = f2bf(b.y); o[6] = f2bf(b.z); o[7] = f2bf(b.w);
    *(u16x8*)(xb + base) = o;
    return;
  }
  const float* w; unsigned short* wt; int R, C, i0;
  if (bid < 577)      { w = Wq; wt = wqt; R = 128; C = 1024; i0 = (bid - 513) * 2048; }
  else if (bid < 641) { w = Wk; wt = wkt; R = 128; C = 1024; i0 = (bid - 577) * 2048; }
  else if (bid < 705) { w = Wv; wt = wvt; R = 128; C = 1024; i0 = (bid - 641) * 2048; }
  else                { w = Wo; wt = wot; R = 1024; C = 128; i0 = (bid - 705) * 2048; }
  int i = i0 + tid * 8;
  int c = i / R, r0 = i - c * R;
  u16x8 o;
#pragma unroll
  for (int j = 0; j < 8; j++) o[j] = f2bf(w[(size_t)(r0 + j) * C + c]);
  *(u16x8*)(wt + i) = o;
}

// ---- fused QKV projection + mask bit-pack ----
// qkv blocks [0,3072): [8192,128]@[128,1024] per weight, K=128 one pass.
// pack blocks [3072,5120): ballot-pack attn_mask into bits (1 bit/elem).
__global__ __launch_bounds__(256) void k_qkv_pack(
    const unsigned short* __restrict__ xb, const unsigned short* __restrict__ wqt,
    const unsigned short* __restrict__ wkt, const unsigned short* __restrict__ wvt,
    unsigned short* __restrict__ qb, unsigned short* __restrict__ kbuf,
    unsigned short* __restrict__ vtb, const void* __restrict__ am,
    const int* __restrict__ flagp, unsigned int* __restrict__ bits) {
  __shared__ unsigned short vt_lds[8192];
  int bid = blockIdx.x;
  int lane = threadIdx.x & 63, w = threadIdx.x >> 6;
  if (bid >= 3072) {
    // ---- mask pack: 8192 elems/block, wave-linear ballot ----
    int flag = *flagp;
    int pb = bid - 3072;
    int wavebase = (pb * 4 + w) * 2048;
    if (flag == 1) {
      const unsigned char* a8 = (const unsigned char*)am;
#pragma unroll 4
      for (int j = 0; j < 32; j++) {
        int i = wavebase + j * 64 + lane;
        unsigned long long bm = __ballot(a8[i] != 0);
        if (lane == 0) bits[i >> 5] = (unsigned int)bm;
        else if (lane == 32) bits[i >> 5] = (unsigned int)(bm >> 32);
      }
    } else {
      const int* a32 = (const int*)am;
#pragma unroll 4
      for (int j = 0; j < 32; j++) {
        int i = wavebase + j * 64 + lane;
        unsigned long long bm = __ballot(a32[i] != 0);
        if (lane == 0) bits[i >> 5] = (unsigned int)bm;
        else if (lane == 32) bits[i >> 5] = (unsigned int)(bm >> 32);
      }
    }
    return;
  }
  // ---- QKV GEMM ----
  int which = bid >> 10;
  int rem = bid & 1023;
  int bx = rem & 127, by = rem >> 7;
  const unsigned short* wt = which == 0 ? wqt : (which == 1 ? wkt : wvt);
  int lo = lane & 15, g = lane >> 4;
  int rbase = bx * 64 + w * 16;
  int colb = by * 128;
  bf16x8 af[4];
  const unsigned short* xrow = xb + (size_t)(rbase + lo) * 128 + g * 8;
#pragma unroll
  for (int s = 0; s < 4; s++) af[s] = ldb(xrow + 32 * s);
  f32x4 acc[8] = {};
#pragma unroll
  for (int c = 0; c < 8; c++) {
    const unsigned short* wrow = wt + (size_t)(colb + c * 16 + lo) * 128 + g * 8;
#pragma unroll
    for (int s = 0; s < 4; s++) acc[c] = mfma16(af[s], ldb(wrow + 32 * s), acc[c]);
  }
  if (which != 2) {
    // Q pre-scaled by log2(e)/sqrt(DH) (exp2-domain softmax downstream)
    float sc = (which == 0) ? 0.12751743f : 1.0f;
#pragma unroll
    for (int c = 0; c < 8; c++) {
#pragma unroll
      for (int r = 0; r < 4; r++) {
        int row = rbase + 4 * g + r;
        int col = colb + c * 16 + lo;
        int b = row >> 11, n = row & (NTOK - 1);
        int h = col >> 7, d = col & 127;
        unsigned short val = f2bf(acc[c][r] * sc);
        size_t bh = (size_t)(b * NH + h);
        if (which == 0) qb[(bh * NTOK + n) * DH + d] = val;
        else            kbuf[(bh * NTOK + n) * DH + d] = val;
      }
    }
    return;
  }
  // V: transpose via LDS, write [bh][d][n] coalesced
#pragma unroll
  for (int c = 0; c < 8; c++) {
#pragma unroll
    for (int r = 0; r < 4; r++) {
      int nl = w * 16 + 4 * g + r;
      int d = c * 16 + lo;
      int boff = d * 128 + ((nl * 2) ^ ((d & 7) << 4));
      *(unsigned short*)((char*)vt_lds + boff) = f2bf(acc[c][r]);
    }
  }
  __syncthreads();
  int t = threadIdx.x;
  int d = t >> 1, half = t & 1;
  int bb = (bx * 64) >> 11;
  int n0 = (bx * 64) & (NTOK - 1);
  size_t bh = (size_t)(bb * NH + by);
  unsigned short* dst = vtb + (bh * DH + d) * NTOK + n0 + half * 32;
  const char* srcb = (const char*)vt_lds + d * 128;
#pragma unroll
  for (int s = 0; s < 4; s++) {
    int lb = (half * 64 + s * 16) ^ ((d & 7) << 4);
    *(u16x8*)(dst + s * 8) = *(const u16x8*)(srcb + lb);
  }
}

// ---- flash attention, KVBLK=64, counted-vmcnt 2-deep pipeline ----
__device__ __forceinline__ void stageK(const char* Kg, char* kl, int w, int lane) {
#pragma unroll
  for (int s = 0; s < 4; s++) {
    int a = s * 4096 + w * 1024 + lane * 16;
    int r = a >> 8;
    int cb = (a & 255) ^ ((r & 7) << 4);
    GLL(Kg + r * 256 + cb, kl + s * 4096 + w * 1024);
  }
}
__device__ __forceinline__ void stageV(const char* Vg, char* vl, int w, int lane) {
#pragma unroll
  for (int s = 0; s < 4; s++) {
    int a = s * 4096 + w * 1024 + lane * 16;
    int r = a >> 7;
    int cb = (a & 127) ^ ((r & 7) << 4);
    GLL(Vg + (size_t)r * (NTOK * 2) + cb, vl + s * 4096 + w * 1024);
  }
}

__global__ __launch_bounds__(256, 2) void k_attn64(
    const unsigned short* __restrict__ qb, const unsigned short* __restrict__ kbuf,
    const unsigned short* __restrict__ vtb, const unsigned int* __restrict__ mbits,
    unsigned short* __restrict__ aout) {
  __shared__ char smem[65536];
  int bid = blockIdx.x;
  // XCD swizzle: bid&7 = b*2+(h>>2)
  int low3 = bid & 7, mid2 = (bid >> 3) & 3, qc = bid >> 5;
  int b = low3 >> 1, h = ((low3 & 1) << 2) | mid2;
  int bh = b * 8 + h;
  int lane = threadIdx.x & 63, w = threadIdx.x >> 6;
  int ql = lane & 31, hi = lane >> 5;
  int q0 = qc * 128 + w * 32;
  const char* Kbase = (const char*)(kbuf + (size_t)bh * NTOK * DH);
  const char* Vbase = (const char*)(vtb + (size_t)bh * NTOK * DH);

  bf16x8 qf[8];
  {
    const unsigned short* qrow = qb + (size_t)bh * NTOK * DH + (size_t)(q0 + ql) * DH + 8 * hi;
#pragma unroll
    for (int s = 0; s < 8; s++) qf[s] = ldb(qrow + 16 * s);
  }
  const uint2* mrow = (const uint2*)(mbits + (size_t)b * (NTOK * NTOK / 32) + (size_t)(q0 + ql) * (NTOK / 32));
  uint2 mm = mrow[0];

  f32x16 o0 = {}, o1 = {}, o2 = {}, o3 = {};
  float m = 0.0f, l = 0.0f;
  char* kl = smem;
  char* vl = smem + 32768;
  int xk = (ql & 7) << 4;

  // prologue: 2 tiles in flight (tile order in vmcnt queue: K0,V0,K1,V1)
  stageK(Kbase, kl, w, lane);
  stageV(Vbase, vl, w, lane);
  stageK(Kbase + 16384, kl + 16384, w, lane);
  stageV(Vbase + 128, vl + 16384, w, lane);

  for (int kt = 0; kt < 32; kt++) {
    int cur = kt & 1;
    const char* kc = kl + cur * 16384;
    const char* vc = vl + cur * 16384;
    if (kt < 31) { asm volatile("s_waitcnt vmcnt(8)" ::: "memory"); }
    else         { asm volatile("s_waitcnt vmcnt(0)" ::: "memory"); }
    __builtin_amdgcn_s_barrier();      // tile kt visible to all waves
    uint2 mm_next = mrow[kt + 1 < 32 ? kt + 1 : 31];
    unsigned int mw0 = mm.x >> (4 * hi), mw1 = mm.y >> (4 * hi);
    // --- S^T = K . Q^T, two 32-key halves ---
    f32x16 sT0 = {}, sT1 = {};
    const char* kr0 = kc + ql * 256;
    const char* kr1 = kc + (32 + ql) * 256;
    __builtin_amdgcn_s_setprio(1);
#pragma unroll
    for (int s = 0; s < 8; s++) {
      int cb = (32 * s + 16 * hi) ^ xk;
      sT0 = mfma32(ldsb(kr0 + cb), qf[s], sT0);
      sT1 = mfma32(ldsb(kr1 + cb), qf[s], sT1);
    }
    __builtin_amdgcn_s_setprio(0);
    // --- masked exp2 softmax (defer-max: m uniform, updated only on overflow) ---
    float sv0[16], sv1[16];
#pragma unroll
    for (int r = 0; r < 16; r++) {
      int cpos = (r & 3) + 8 * (r >> 2);
      sv0[r] = ((mw0 >> cpos) & 1u) ? sT0[r] : -3.0e38f;
      sv1[r] = ((mw1 >> cpos) & 1u) ? sT1[r] : -3.0e38f;
    }
    float ps = 0.f;
#pragma unroll
    for (int r = 0; r < 16; r++) { sv0[r] = exp2a(sv0[r] - m); ps += sv0[r]; }
#pragma unroll
    for (int r = 0; r < 16; r++) { sv1[r] = exp2a(sv1[r] - m); ps += sv1[r]; }
    l += ps;
    bool big = __any(ps > 65536.0f);
    // --- pack bf16 + half-exchange -> PV A-fragments ---
    unsigned int w8a[8], w8b[8], pa[8], pb[8];
#pragma unroll
    for (int j = 0; j < 8; j++) {
      w8a[j] = cvtpk(sv0[2 * j], sv0[2 * j + 1]);
      w8b[j] = cvtpk(sv1[2 * j], sv1[2 * j + 1]);
    }
#pragma unroll
    for (int j = 0; j < 8; j++) {
      pa[j] = __shfl_xor((int)w8a[j], 32, 64);
      pb[j] = __shfl_xor((int)w8b[j], 32, 64);
    }
    u32x4 ta0, ta1, tb0, tb1;
    if (hi) {
      ta0 = u32x4{pa[2], pa[3], w8a[2], w8a[3]};
      ta1 = u32x4{pa[6], pa[7], w8a[6], w8a[7]};
      tb0 = u32x4{pb[2], pb[3], w8b[2], w8b[3]};
      tb1 = u32x4{pb[6], pb[7], w8b[6], w8b[7]};
    } else {
      ta0 = u32x4{w8a[0], w8a[1], pa[0], pa[1]};
      ta1 = u32x4{w8a[4], w8a[5], pa[4], pa[5]};
      tb0 = u32x4{w8b[0], w8b[1], pb[0], pb[1]};
      tb1 = u32x4{w8b[4], w8b[5], pb[4], pb[5]};
    }
    bf16x8 fkA0 = __builtin_bit_cast(bf16x8, ta0);
    bf16x8 fkA1 = __builtin_bit_cast(bf16x8, ta1);
    bf16x8 fkB0 = __builtin_bit_cast(bf16x8, tb0);
    bf16x8 fkB1 = __builtin_bit_cast(bf16x8, tb1);
    // --- PV from swizzled LDS V tile ---
    __builtin_amdgcn_s_setprio(1);
    {
      const char* vr0 = vc + (ql + 0) * 128;
      const char* vr1 = vc + (ql + 32) * 128;
      const char* vr2 = vc + (ql + 64) * 128;
      const char* vr3 = vc + (ql + 96) * 128;
      int c0 = (16 * hi) ^ xk, c1 = (32 + 16 * hi) ^ xk;
      int c2 = (64 + 16 * hi) ^ xk, c3 = (96 + 16 * hi) ^ xk;
      o0 = mfma32(fkA0, ldsb(vr0 + c0), o0);
      o1 = mfma32(fkA0, ldsb(vr1 + c0), o1);
      o2 = mfma32(fkA0, ldsb(vr2 + c0), o2);
      o3 = mfma32(fkA0, ldsb(vr3 + c0), o3);
      o0 = mfma32(fkA1, ldsb(vr0 + c1), o0);
      o1 = mfma32(fkA1, ldsb(vr1 + c1), o1);
      o2 = mfma32(fkA1, ldsb(vr2 + c1), o2);
      o3 = mfma32(fkA1, ldsb(vr3 + c1), o3);
      o0 = mfma32(fkB0, ldsb(vr0 + c2), o0);
      o1 = mfma32(fkB0, ldsb(vr1 + c2), o1);
      o2 = mfma32(fkB0, ldsb(vr2 + c2), o2);
      o3 = mfma32(fkB0, ldsb(vr3 + c2), o3);
      o0 = mfma32(fkB1, ldsb(vr0 + c3), o0);
      o1 = mfma32(fkB1, ldsb(vr1 + c3), o1);
      o2 = mfma32(fkB1, ldsb(vr2 + c3), o2);
      o3 = mfma32(fkB1, ldsb(vr3 + c3), o3);
    }
    __builtin_amdgcn_s_setprio(0);
    if (big) {                 // uniform overflow guard: o/l ratio invariant
      const float c = 1.52587890625e-05f;  // 2^-16
      m += 16.0f; l *= c;
#pragma unroll
      for (int r = 0; r < 16; r++) { o0[r] *= c; o1[r] *= c; o2[r] *= c; o3[r] *= c; }
    }
    __builtin_amdgcn_s_barrier();      // all waves done reading cur buffers
    if (kt + 2 < 32) {                 // stage tile kt+2 into just-freed buffers
      stageK(Kbase + (size_t)(kt + 2) * 16384, kl + cur * 16384, w, lane);
      stageV(Vbase + (size_t)(kt + 2) * 128, vl + cur * 16384, w, lane);
    }
    mm = mm_next;
  }
  // --- finalize ---
  float lj = l + __shfl_xor(l, 32, 64);
  float linv = lj > 0.f ? 1.0f / lj : 0.0f;
  float li[16];
#pragma unroll
  for (int r = 0; r < 16; r++) {
    int qr = (r & 3) + 8 * (r >> 2) + 4 * hi;
    li[r] = __shfl(linv, qr, 64);
  }
  unsigned short* obase = aout + (size_t)b * NTOK * (NH * DH) + (size_t)h * DH + ql;
#pragma unroll
  for (int r = 0; r < 16; r++) {
    int qn = q0 + (r & 3) + 8 * (r >> 2) + 4 * hi;
    unsigned short* op = obase + (size_t)qn * (NH * DH);
    op[0]  = f2bf(o0[r] * li[r]);
    op[32] = f2bf(o1[r] * li[r]);
    op[64] = f2bf(o2[r] * li[r]);
    op[96] = f2bf(o3[r] * li[r]);
  }
}

// ---- out-proj (K=1024) + bias + residual + LayerNorm + SiLU + node_mask ----
__global__ __launch_bounds__(128) void k_gemm3(
    const unsigned short* __restrict__ aout, const unsigned short* __restrict__ wot,
    const float* __restrict__ x, const float* __restrict__ bo,
    const float* __restrict__ gamma, const float* __restrict__ beta,
    const void* __restrict__ nmask, const int* __restrict__ flagp,
    float* __restrict__ out) {
  int flag = *flagp;
  int lane = threadIdx.x & 63, w = threadIdx.x >> 6;
  int lo = lane & 15, g = lane >> 4;
  int rowb = blockIdx.x * 32 + w * 16;
  f32x4 acc[8] = {};
  const unsigned short* arow = aout + (size_t)(rowb + lo) * 1024 + g * 8;
  for (int ks = 0; ks < 32; ks++) {
    bf16x8 af = ldb(arow + 32 * ks);
#pragma unroll
    for (int t = 0; t < 8; t++) {
      bf16x8 bf = ldb(wot + (size_t)(t * 16 + lo) * 1024 + g * 8 + 32 * ks);
      acc[t] = mfma16(af, bf, acc[t]);
    }
  }
  float gv[8], bv[8], bov[8];
#pragma unroll
  for (int t = 0; t < 8; t++) {
    int col = t * 16 + lo;
    gv[t] = gamma[col]; bv[t] = beta[col]; bov[t] = bo[col];
  }
  float y[8][4];
#pragma unroll
  for (int t = 0; t < 8; t++) {
#pragma unroll
    for (int r = 0; r < 4; r++) {
      int row = rowb + 4 * g + r;
      y[t][r] = acc[t][r] + bov[t] + x[(size_t)row * 128 + t * 16 + lo];
    }
  }
#pragma unroll
  for (int r = 0; r < 4; r++) {
    int row = rowb + 4 * g + r;
    float s = 0.f;
#pragma unroll
    for (int t = 0; t < 8; t++) s += y[t][r];
    s += __shfl_xor(s, 1, 64); s += __shfl_xor(s, 2, 64);
    s += __shfl_xor(s, 4, 64); s += __shfl_xor(s, 8, 64);
    float mu = s * 0.0078125f;
    float vs = 0.f;
#pragma unroll
    for (int t = 0; t < 8; t++) { float d = y[t][r] - mu; vs += d * d; }
    vs += __shfl_xor(vs, 1, 64); vs += __shfl_xor(vs, 2, 64);
    vs += __shfl_xor(vs, 4, 64); vs += __shfl_xor(vs, 8, 64);
    float rstd = rsqrtf(vs * 0.0078125f + 1e-5f);
    float nm = mask_at(nmask, flag, row) ? 1.0f : 0.0f;
#pragma unroll
    for (int t = 0; t < 8; t++) {
      float z = (y[t][r] - mu) * rstd * gv[t] + bv[t];
      z = z / (1.0f + __expf(-z));          // SiLU
      out[(size_t)row * 128 + t * 16 + lo] = z * nm;
    }
  }
}

extern "C" void kernel_launch(void* const* d_in, const int* in_sizes, int n_in,
                              void* d_out, int out_size, void* d_ws, size_t ws_size,
                              hipStream_t stream) {
  (void)in_sizes; (void)n_in; (void)out_size;
  const float* x = (const float*)d_in[0];
  const void* amask = d_in[1];
  const void* nmask = d_in[2];
  const float* Wq = (const float*)d_in[3];
  const float* Wk = (const float*)d_in[4];
  const float* Wv = (const float*)d_in[5];
  const float* Wo = (const float*)d_in[6];
  const float* bo = (const float*)d_in[7];
  const float* gamma = (const float*)d_in[8];
  const float* beta = (const float*)d_in[9];
  float* out = (float*)d_out;
  char* ws = (char*)d_ws;

  constexpr size_t OFF_FLAG = 0;
  constexpr size_t OFF_XB   = 256;
  constexpr size_t OFF_WQT  = OFF_XB  + (size_t)8192 * 128 * 2;
  constexpr size_t OFF_WKT  = OFF_WQT + (size_t)1024 * 128 * 2;
  constexpr size_t OFF_WVT  = OFF_WKT + (size_t)1024 * 128 * 2;
  constexpr size_t OFF_WOT  = OFF_WVT + (size_t)1024 * 128 * 2;
  constexpr size_t OFF_BITS = OFF_WOT + (size_t)1024 * 128 * 2;
  constexpr size_t OFF_QB   = OFF_BITS + (size_t)NB * NTOK * NTOK / 8;
  constexpr size_t OFF_KB   = OFF_QB  + (size_t)NB * NH * NTOK * DH * 2;
  constexpr size_t OFF_VTB  = OFF_KB  + (size_t)NB * NH * NTOK * DH * 2;
  constexpr size_t OFF_AO   = OFF_VTB + (size_t)NB * NH * NTOK * DH * 2;
  constexpr size_t TOTAL    = OFF_AO  + (size_t)NB * NTOK * NH * DH * 2;
  if (ws_size < TOTAL) return;

  int* flag = (int*)(ws + OFF_FLAG);
  unsigned short* xb  = (unsigned short*)(ws + OFF_XB);
  unsigned short* wqt = (unsigned short*)(ws + OFF_WQT);
  unsigned short* wkt = (unsigned short*)(ws + OFF_WKT);
  unsigned short* wvt = (unsigned short*)(ws + OFF_WVT);
  unsigned short* wot = (unsigned short*)(ws + OFF_WOT);
  unsigned int* bits  = (unsigned int*)(ws + OFF_BITS);
  unsigned short* qb  = (unsigned short*)(ws + OFF_QB);
  unsigned short* kbf = (unsigned short*)(ws + OFF_KB);
  unsigned short* vtb = (unsigned short*)(ws + OFF_VTB);
  unsigned short* ao  = (unsigned short*)(ws + OFF_AO);

  k_prep<<<769, 256, 0, stream>>>(x, Wq, Wk, Wv, Wo, (const unsigned int*)amask,
                                  xb, wqt, wkt, wvt, wot, flag);
  k_qkv_pack<<<5120, 256, 0, stream>>>(xb, wqt, wkt, wvt, qb, kbf, vtb,
                                       amask, flag, bits);
  k_attn64<<<512, 256, 0, stream>>>(qb, kbf, vtb, bits, ao);
  k_gemm3<<<256, 128, 0, stream>>>(ao, wot, x, bo, gamma, beta, nmask, flag, out);
}